// Round 12
// baseline (659.178 us; speedup 1.0000x reference)
//
#include <hip/hip_runtime.h>
#include <hip/hip_bf16.h>

typedef unsigned short u16;
typedef __bf16 bf16x8 __attribute__((ext_vector_type(8)));
typedef float f32x4 __attribute__((ext_vector_type(4)));
typedef float f32x16 __attribute__((ext_vector_type(16)));

#define DIMC  2048
#define NH    16
#define HD    128
#define BSZ   2
#define SEQ   4096
#define MTOK  (BSZ*SEQ)   /* 8192 tokens */

// scale * log2(e): folded into Q at rmsrope time
#define SCALE_L2E (0.08838834764831845f * 1.4426950408889634f)

__device__ __forceinline__ u16 f2bf(float f) {
  unsigned u = __float_as_uint(f);
  u += 0x7fff + ((u >> 16) & 1);   // RTNE
  return (u16)(u >> 16);
}
__device__ __forceinline__ float bf2f(u16 b) {
  return __uint_as_float(((unsigned)b) << 16);
}

__device__ __forceinline__ void gload_lds16(const void* g, void* l) {
  __builtin_amdgcn_global_load_lds(
      (const __attribute__((address_space(1))) void*)g,
      (__attribute__((address_space(3))) void*)l, 16, 0, 0);
}

#define BAR() __builtin_amdgcn_s_barrier()
#define ASM_VMCNT(n) do { asm volatile("s_waitcnt vmcnt(" #n ")" ::: "memory"); \
                          __builtin_amdgcn_sched_barrier(0); } while (0)
#define ASM_LGK0()   do { asm volatile("s_waitcnt lgkmcnt(0)" ::: "memory");    \
                          __builtin_amdgcn_sched_barrier(0); } while (0)

// ---------------- cast f32 -> bf16 ----------------
__global__ __launch_bounds__(256) void cast_bf16_k(const float* __restrict__ in,
                                                   u16* __restrict__ out, int n) {
  int i = (blockIdx.x * 256 + threadIdx.x) * 4;
  if (i >= n) return;
  float4 v = *(const float4*)(in + i);
  ushort4 o;
  o.x = f2bf(v.x); o.y = f2bf(v.y); o.z = f2bf(v.z); o.w = f2bf(v.w);
  *(ushort4*)(out + i) = o;
}

// cast the 4 weight matrices in one dispatch (z selects the matrix)
__global__ __launch_bounds__(256) void cast_w4_k(
    const float* __restrict__ w0, const float* __restrict__ w1,
    const float* __restrict__ w2, const float* __restrict__ w3,
    u16* __restrict__ out, int n) {
  const int z = blockIdx.z;
  const float* src = (z == 0) ? w0 : (z == 1) ? w1 : (z == 2) ? w2 : w3;
  u16* dst = out + (size_t)z * n;
  int i = (blockIdx.x * 256 + threadIdx.x) * 4;
  if (i >= n) return;
  float4 v = *(const float4*)(src + i);
  ushort4 o;
  o.x = f2bf(v.x); o.y = f2bf(v.y); o.z = f2bf(v.z); o.w = f2bf(v.w);
  *(ushort4*)(dst + i) = o;
}

// ---------------- 256x256 8-phase GEMM (T2+T3+T4+T5) ----------------
// z==2 (the V projection) writes its output DIRECTLY TRANSPOSED to vT via an
// LDS bounce (the 128 KiB As/Bs buffer == one 256x256 bf16 tile exactly).
#define AsBuf(d, h) (SMEM[(d) * 2 + (h)])
#define BsBuf(d, h) (SMEM[4 + (d) * 2 + (h)])

#define STG_A(d, kt, h)                                                        \
  { const u16* s_ = Ag + (size_t)(h) * khalf + (size_t)(kt) * 64;              \
    gload_lds16(s_ + at0, (u16*)AsBuf(d, h) + tid * 8);                        \
    gload_lds16(s_ + at1, (u16*)AsBuf(d, h) + (tid + 512) * 8); }
#define STG_B(d, kt, h)                                                        \
  { const u16* s_ = Bg + (size_t)(h) * khalf + (size_t)(kt) * 64;              \
    gload_lds16(s_ + at0, (u16*)BsBuf(d, h) + tid * 8);                        \
    gload_lds16(s_ + at1, (u16*)BsBuf(d, h) + (tid + 512) * 8); }

#define GPHASE(bb, q, STAGE_CODE, TAIL_CODE)                                   \
  {                                                                            \
    if ((q) == 0) {                                                            \
      _Pragma("unroll") for (int fc = 0; fc < 4; fc++)                         \
        _Pragma("unroll") for (int ks = 0; ks < 2; ks++)                       \
          bfr[fc][ks] = *(const bf16x8*)((const char*)BsBuf(bb, wc >> 1) +     \
              rbB + fc * 2048 + colr[ks]);                                     \
    }                                                                          \
    _Pragma("unroll") for (int e = 0; e < 2; e++)                              \
      _Pragma("unroll") for (int ks = 0; ks < 2; ks++)                         \
        afr[e][ks] = *(const bf16x8*)((const char*)AsBuf(bb, wr) +             \
            rbA + (2 * (q) + e) * 2048 + colr[ks]);                            \
    STAGE_CODE;                                                                \
    BAR();                                                                     \
    ASM_LGK0();                                                                \
    __builtin_amdgcn_s_setprio(1);                                             \
    _Pragma("unroll") for (int e = 0; e < 2; e++)                              \
      _Pragma("unroll") for (int fc = 0; fc < 4; fc++)                         \
        _Pragma("unroll") for (int ks = 0; ks < 2; ks++)                       \
          acc[2 * (q) + e][fc] = __builtin_amdgcn_mfma_f32_16x16x32_bf16(      \
              afr[e][ks], bfr[fc][ks], acc[2 * (q) + e][fc], 0, 0, 0);         \
    __builtin_amdgcn_s_setprio(0);                                             \
    TAIL_CODE;                                                                 \
    BAR();                                                                     \
    __builtin_amdgcn_sched_barrier(0);                                         \
  }

template<bool OUT_F32>
__global__ __launch_bounds__(512, 2) void gemm256_k(
    const u16* __restrict__ A, const u16* __restrict__ Bt,
    const float* __restrict__ b0, const float* __restrict__ b1,
    const float* __restrict__ b2, void* __restrict__ Cout,
    u16* __restrict__ vTout,
    size_t wstride, size_t ostride, int Ndim, int Kdim) {
  __shared__ __align__(16) u16 SMEM[8][128 * 64];
  const int tid = threadIdx.x;
  const int lane = tid & 63, wid = tid >> 6;
  const int wr = wid >> 2, wc = wid & 3;          // 2M x 4N waves
  const int l15 = lane & 15, lg = lane >> 4;
  const int z = blockIdx.z;

  const u16* W = Bt + (size_t)z * wstride;
  const float* bias = (z == 0) ? b0 : (z == 1 ? b1 : b2);

  const int flat = blockIdx.y * gridDim.x + blockIdx.x;
  const int cpx = (gridDim.x * gridDim.y) >> 3;
  const int swz = (flat & 7) * cpx + (flat >> 3);
  const int bn = (swz % gridDim.x) * 256;
  const int bm = (swz / gridDim.x) * 256;

  const u16* Ag = A + (size_t)bm * Kdim;
  const u16* Bg = W + (size_t)bn * Kdim;
  const size_t khalf = (size_t)128 * Kdim;

  const int r0 = tid >> 3, cc0 = tid & 7;
  const size_t at0 = (size_t)r0 * Kdim + (size_t)((cc0 ^ (r0 & 7)) * 8);
  const size_t at1 = at0 + (size_t)64 * Kdim;

  const int swzl = (l15 & 7) << 4;
  int colr[2];
  colr[0] = (0 * 64 + lg * 16) ^ swzl;
  colr[1] = (1 * 64 + lg * 16) ^ swzl;
  const int rbA = l15 * 128;
  const int rbB = (wc & 1) * 8192 + l15 * 128;

  f32x4 acc[8][4];
#pragma unroll
  for (int i = 0; i < 8; i++)
#pragma unroll
    for (int j = 0; j < 4; j++) acc[i][j] = f32x4{0.f, 0.f, 0.f, 0.f};
  bf16x8 bfr[4][2], afr[2][2];

  STG_A(0, 0, 0); STG_A(0, 0, 1);
  STG_B(0, 0, 0); STG_B(0, 0, 1);
  STG_B(1, 1, 0); STG_B(1, 1, 1);
  ASM_VMCNT(4);
  BAR();

  const int niter = Kdim / 128 - 1;
#pragma unroll 1
  for (int k = 0; k < niter; ++k) {
    const int t = 2 * k;
    GPHASE(0, 0, STG_A(1, t + 1, 0), (void)0);
    GPHASE(0, 1, STG_A(1, t + 1, 1), (void)0);
    GPHASE(0, 2, STG_B(0, t + 2, 0), (void)0);
    GPHASE(0, 3, STG_B(0, t + 2, 1), ASM_VMCNT(4));
    GPHASE(1, 0, STG_A(0, t + 2, 0), (void)0);
    GPHASE(1, 1, STG_A(0, t + 2, 1), (void)0);
    GPHASE(1, 2, STG_B(1, t + 3, 0), (void)0);
    GPHASE(1, 3, STG_B(1, t + 3, 1), ASM_VMCNT(4));
  }
  {
    const int tl = Kdim / 64 - 1;
    GPHASE(0, 0, STG_A(1, tl, 0), (void)0);
    GPHASE(0, 1, STG_A(1, tl, 1), (void)0);
    GPHASE(0, 2, (void)0, (void)0);
    GPHASE(0, 3, (void)0, ASM_VMCNT(0));
    GPHASE(1, 0, (void)0, (void)0);
    GPHASE(1, 1, (void)0, (void)0);
    GPHASE(1, 2, (void)0, (void)0);
    GPHASE(1, 3, (void)0, (void)0);
  }

  if (!OUT_F32 && z == 2) {
    // transposed write of the V projection via LDS bounce.
    u16* Ts = &SMEM[0][0];
#pragma unroll
    for (int fc = 0; fc < 4; fc++) {
      const int ch = wc * 64 + fc * 16 + l15;
      const float bv = bias[bn + ch];
      const int chx = (ch & 31) << 4;
#pragma unroll
      for (int fr = 0; fr < 8; fr++) {
        const int tok2 = (wr * 128 + fr * 16 + lg * 4) * 2;
        ushort4 w;
        w.x = f2bf(acc[fr][fc][0] + bv);
        w.y = f2bf(acc[fr][fc][1] + bv);
        w.z = f2bf(acc[fr][fc][2] + bv);
        w.w = f2bf(acc[fr][fc][3] + bv);
        *(ushort4*)((char*)Ts + ch * 512 + (tok2 ^ chx)) = w;
      }
    }
    __syncthreads();
    const int b_ = bm >> 12, sm = bm & (SEQ - 1);
    const int l5 = tid & 31, g5 = tid >> 5;     // 16 groups of 32 lanes
#pragma unroll
    for (int i = 0; i < 16; i++) {
      const int ch = i * 16 + g5;
      const uint4 dv = *(const uint4*)((const char*)Ts + ch * 512 +
                                       ((l5 * 16) ^ ((ch & 31) << 4)));
      *(uint4*)(vTout + (size_t)(b_ * DIMC + bn + ch) * SEQ + sm + l5 * 8) = dv;
    }
  } else {
#pragma unroll
    for (int fc = 0; fc < 4; fc++) {
      const int cj = bn + wc * 64 + fc * 16 + l15;
      const float bv = bias[cj];
#pragma unroll
      for (int fr = 0; fr < 8; fr++) {
        const int row0 = bm + wr * 128 + fr * 16 + lg * 4;
#pragma unroll
        for (int r = 0; r < 4; r++) {
          float v = acc[fr][fc][r] + bv;
          if (OUT_F32)
            ((float*)Cout)[(size_t)z * ostride + (size_t)(row0 + r) * Ndim + cj] = v;
          else
            ((u16*)Cout)[(size_t)z * ostride + (size_t)(row0 + r) * Ndim + cj] = f2bf(v);
        }
      }
    }
  }
}

// ---------------- fused RMSNorm + RoPE (in-place on q,k; bf16 storage) ----------------
__global__ __launch_bounds__(256) void rmsrope_k(
    u16* __restrict__ qk, const float* __restrict__ gq, const float* __restrict__ gk,
    const float* __restrict__ freqs) {
  const int t = blockIdx.x;        // token
  const int s = t & (SEQ - 1);
  const int tid = threadIdx.x;
  __shared__ float red[8];

  for (int which = 0; which < 2; ++which) {
    u16* row = qk + (size_t)which * ((size_t)MTOK * DIMC) + (size_t)t * DIMC;
    const float* g = which ? gk : gq;
    const float oscale = which ? 1.0f : SCALE_L2E;
    uint4 raw = *(const uint4*)(row + tid * 8);
    const u16* rb = (const u16*)&raw;
    float v[8], ss = 0.f;
#pragma unroll
    for (int e = 0; e < 8; e++) { v[e] = bf2f(rb[e]); ss += v[e] * v[e]; }
#pragma unroll
    for (int m = 1; m < 64; m <<= 1) ss += __shfl_xor(ss, m);
    if ((tid & 63) == 0) red[which * 4 + (tid >> 6)] = ss;
    __syncthreads();
    float tot = red[which * 4] + red[which * 4 + 1] + red[which * 4 + 2] + red[which * 4 + 3];
    float rms = rsqrtf(tot * (1.0f / (float)DIMC) + 1e-6f);
    const int ch0 = tid * 8;
    const int d0 = ch0 & (HD - 1);
    u16 ob[8];
#pragma unroll
    for (int p = 0; p < 4; p++) {
      float fr = freqs[s * (HD / 2) + (d0 >> 1) + p];
      float cs = cosf(fr), sn = sinf(fr);
      float e = v[2 * p] * rms * g[ch0 + 2 * p];
      float o = v[2 * p + 1] * rms * g[ch0 + 2 * p + 1];
      ob[2 * p]     = f2bf((e * cs - o * sn) * oscale);
      ob[2 * p + 1] = f2bf((e * sn + o * cs) * oscale);
    }
    *(uint4*)(row + tid * 8) = *(const uint4*)ob;
    __syncthreads();
  }
}

// ---------------- flash attention: 32x32 swapped-QK^T, in-register softmax ----
// R8 schedule (proven 354us). VALU-diet: all LDS read addresses are
// precomputed per-lane bases + compile-time offsets (Ks[2]/Vs[2] single
// arrays -> buffer select via offset imm), persistent zero-C register for
// score init, lq cross-half reduction deferred to epilogue.
#define STAGE(kb, vb, kv0)                                                     \
  _Pragma("unroll") for (int it = 0; it < 4; ++it) {                           \
    const int c = it * 256 + tid;                                              \
    { const int rr = c >> 4, ss = c & 15;                                      \
      gload_lds16(Kp + (size_t)((kv0) + rr) * DIMC + ((ss ^ (rr & 15)) * 8),   \
                  (u16*)Ks + (kb) * 8192 + c * 8); }                           \
    { const int rr = c >> 3, ss = c & 7;                                       \
      gload_lds16(Vp + (size_t)rr * SEQ + (kv0) + ((ss ^ (rr & 7)) * 8),       \
                  (u16*)Vs + (vb) * 8192 + c * 8); }                           \
  }

#define CROW(r) (((r) & 3) + 8 * ((r) >> 2) + 4 * hi)

// KOFF/VOFF are compile-time byte offsets (0 or 16384) selecting the buffer.
#define COMPUTE(KOFF, VOFF)                                                    \
  {                                                                            \
    f32x16 s0, s1;                                                             \
    {                                                                          \
      const bf16x8 k0 = *(const bf16x8*)(kbase0 + (KOFF));                     \
      const bf16x8 k1 = *(const bf16x8*)(kbase0 + (KOFF) + 8192);              \
      s0 = __builtin_amdgcn_mfma_f32_32x32x16_bf16(k0, qf[0], Zc, 0, 0, 0);    \
      s1 = __builtin_amdgcn_mfma_f32_32x32x16_bf16(k1, qf[0], Zc, 0, 0, 0);    \
    }                                                                          \
    _Pragma("unroll") for (int j = 1; j < 8; ++j) {                            \
      const bf16x8 k0 = *(const bf16x8*)(kbase[j - 1] + (KOFF));               \
      const bf16x8 k1 = *(const bf16x8*)(kbase[j - 1] + (KOFF) + 8192);        \
      s0 = __builtin_amdgcn_mfma_f32_32x32x16_bf16(k0, qf[j], s0, 0, 0, 0);    \
      s1 = __builtin_amdgcn_mfma_f32_32x32x16_bf16(k1, qf[j], s1, 0, 0, 0);    \
    }                                                                          \
    float mt[16];                                                              \
    _Pragma("unroll") for (int r = 0; r < 16; r++) mt[r] = fmaxf(s0[r], s1[r]); \
    _Pragma("unroll") for (int st = 8; st > 0; st >>= 1)                       \
      _Pragma("unroll") for (int r = 0; r < st; r++) mt[r] = fmaxf(mt[r], mt[r + st]); \
    float rmax = fmaxf(mt[0], __shfl_xor(mt[0], 32));                          \
    if (!__all(rmax - mq <= 8.0f)) {                                           \
      const float mn = fmaxf(mq, rmax);                                        \
      const float al = exp2f(mq - mn);                                         \
      mq = mn; lq *= al;                                                       \
      _Pragma("unroll") for (int r = 0; r < 16; r++) {                         \
        const float ar = __shfl(al, CROW(r));                                  \
        _Pragma("unroll") for (int d = 0; d < 4; d++) accO[d][r] *= ar;        \
      }                                                                        \
    }                                                                          \
    float p[32]; float rsum = 0.f;                                             \
    _Pragma("unroll") for (int r = 0; r < 16; r++) {                           \
      p[r] = exp2f(s0[r] - mq); rsum += p[r];                                  \
      p[16 + r] = exp2f(s1[r] - mq); rsum += p[16 + r];                        \
    }                                                                          \
    lq += rsum;                                                                \
    bf16x8 pa[4];                                                              \
    _Pragma("unroll") for (int kb = 0; kb < 2; kb++) {                         \
      unsigned A0, A1, A2, A3, A4, A5, A6, A7;                                 \
      const int bp = kb * 16;                                                  \
      asm("v_cvt_pk_bf16_f32 %0, %1, %2" : "=v"(A0) : "v"(p[bp+0]), "v"(p[bp+1])); \
      asm("v_cvt_pk_bf16_f32 %0, %1, %2" : "=v"(A1) : "v"(p[bp+2]), "v"(p[bp+3])); \
      asm("v_cvt_pk_bf16_f32 %0, %1, %2" : "=v"(A2) : "v"(p[bp+4]), "v"(p[bp+5])); \
      asm("v_cvt_pk_bf16_f32 %0, %1, %2" : "=v"(A3) : "v"(p[bp+6]), "v"(p[bp+7])); \
      asm("v_cvt_pk_bf16_f32 %0, %1, %2" : "=v"(A4) : "v"(p[bp+8]), "v"(p[bp+9])); \
      asm("v_cvt_pk_bf16_f32 %0, %1, %2" : "=v"(A5) : "v"(p[bp+10]), "v"(p[bp+11])); \
      asm("v_cvt_pk_bf16_f32 %0, %1, %2" : "=v"(A6) : "v"(p[bp+12]), "v"(p[bp+13])); \
      asm("v_cvt_pk_bf16_f32 %0, %1, %2" : "=v"(A7) : "v"(p[bp+14]), "v"(p[bp+15])); \
      asm("v_permlane32_swap_b32 %0, %1" : "+v"(A0), "+v"(A2));                \
      asm("v_permlane32_swap_b32 %0, %1" : "+v"(A1), "+v"(A3));                \
      asm("v_permlane32_swap_b32 %0, %1" : "+v"(A4), "+v"(A6));                \
      asm("v_permlane32_swap_b32 %0, %1" : "+v"(A5), "+v"(A7));                \
      union { unsigned u[4]; bf16x8 v; } f0, f1;                               \
      f0.u[0] = A0; f0.u[1] = A1; f0.u[2] = A2; f0.u[3] = A3;                  \
      f1.u[0] = A4; f1.u[1] = A5; f1.u[2] = A6; f1.u[3] = A7;                  \
      pa[kb * 2] = f0.v; pa[kb * 2 + 1] = f1.v;                                \
    }                                                                          \
    _Pragma("unroll") for (int c = 0; c < 4; c++) {                            \
      _Pragma("unroll") for (int d = 0; d < 4; d++) {                          \
        const bf16x8 vb = *(const bf16x8*)(vbase[c] + d * 4096 + (VOFF));      \
        accO[d] = __builtin_amdgcn_mfma_f32_32x32x16_bf16(pa[c], vb, accO[d], 0, 0, 0); \
      }                                                                        \
    }                                                                          \
  }

__global__ __launch_bounds__(256, 2) void attn_k(
    const u16* __restrict__ qbuf, const u16* __restrict__ kbuf,
    const u16* __restrict__ vT, u16* __restrict__ obuf) {
  const int flat = blockIdx.y * gridDim.x + blockIdx.x;   // 1024 total
  const int swz = (flat & 7) * 128 + (flat >> 3);         // XCD chunks of 128
  const int bh = swz >> 5, b = bh >> 4, h = bh & 15;
  const int q0 = (swz & 31) * 128;
  const int tid = threadIdx.x, lane = tid & 63, wid = tid >> 6;
  const int l31 = lane & 31, hi = lane >> 5;

  __shared__ __align__(16) u16 Ks[2][64 * 128];   // buffer stride 16384 B
  __shared__ __align__(16) u16 Vs[2][128 * 64];   // buffer stride 16384 B

  const size_t qkbase = (size_t)(b * SEQ) * DIMC + h * HD;
  const u16* Qp = qbuf + qkbase;
  const u16* Kp = kbuf + qkbase;
  const u16* Vp = vT + (size_t)(b * DIMC + h * HD) * SEQ;

  bf16x8 qf[8];
  const int qrow = q0 + wid * 32 + l31;
#pragma unroll
  for (int j = 0; j < 8; ++j)
    qf[j] = *(const bf16x8*)(Qp + (size_t)qrow * DIMC + j * 16 + hi * 8);

  // precomputed per-lane LDS read bases (loop-invariant; buffer/k1/d offsets
  // are compile-time immediates on top of these)
  const char* kbase0 = (const char*)Ks + l31 * 256 +
                       ((hi * 16) ^ ((l31 & 15) << 4));
  const char* kbase[7];
#pragma unroll
  for (int j = 1; j < 8; ++j)
    kbase[j - 1] = (const char*)Ks + l31 * 256 +
                   ((j * 32 + hi * 16) ^ ((l31 & 15) << 4));
  const char* vbase[4];
#pragma unroll
  for (int c = 0; c < 4; ++c)
    vbase[c] = (const char*)Vs + l31 * 128 +
               ((c * 32 + hi * 16) ^ ((l31 & 7) << 4));

  float mq = -1e30f, lq = 0.f;
  f32x16 accO[4];
#pragma unroll
  for (int d = 0; d < 4; d++)
#pragma unroll
    for (int i = 0; i < 16; i++) accO[d][i] = 0.f;
  f32x16 Zc;
#pragma unroll
  for (int i = 0; i < 16; i++) Zc[i] = 0.f;
  asm volatile("" : "+v"(Zc));   // keep Zc materialized once

  STAGE(0, 0, 0);
  __syncthreads();

#pragma unroll 1
  for (int t = 0; t < SEQ / 64; t += 2) {
    STAGE(1, 1, (t + 1) * 64);
    COMPUTE(0, 0);
    __syncthreads();
    if (t + 2 < SEQ / 64) STAGE(0, 0, (t + 2) * 64);
    COMPUTE(16384, 16384);
    __syncthreads();
  }

  lq += __shfl_xor(lq, 32);      // deferred cross-half reduction
  const float linv = 1.0f / lq;
  u16* Op = obuf + (size_t)(b * SEQ + q0 + wid * 32) * DIMC + h * HD;
#pragma unroll
  for (int r = 0; r < 16; r++) {
    const float lr = __shfl(linv, CROW(r));
    const int orow = CROW(r);
#pragma unroll
    for (int d = 0; d < 4; d++)
      Op[(size_t)orow * DIMC + d * 32 + l31] = f2bf(accO[d][r] * lr);
  }
}

// ---------------- launch ----------------
extern "C" void kernel_launch(void* const* d_in, const int* in_sizes, int n_in,
                              void* d_out, int out_size, void* d_ws, size_t ws_size,
                              hipStream_t stream) {
  const float* x     = (const float*)d_in[0];
  const float* freqs = (const float*)d_in[2];
  const float* wq = (const float*)d_in[3];
  const float* bq = (const float*)d_in[4];
  const float* wk = (const float*)d_in[5];
  const float* bk = (const float*)d_in[6];
  const float* wv = (const float*)d_in[7];
  const float* bv = (const float*)d_in[8];
  const float* wo = (const float*)d_in[9];
  const float* bo = (const float*)d_in[10];
  const float* gq = (const float*)d_in[11];
  const float* gk = (const float*)d_in[12];

  const size_t WS = (size_t)DIMC * DIMC;       // weight elems
  const size_t QS = (size_t)MTOK * DIMC;       // activation elems
  char* ws = (char*)d_ws;
  u16* xb  = (u16*)ws;  ws += QS * 2;
  u16* wb  = (u16*)ws;  ws += 4 * WS * 2;
  u16* qkv = (u16*)ws;  ws += 3 * QS * 2;
  u16* vT  = (u16*)ws;  ws += QS * 2;
  u16* ob  = (u16*)ws;  ws += QS * 2;

  cast_bf16_k<<<(int)(QS / 1024), 256, 0, stream>>>(x, xb, (int)QS);
  cast_w4_k<<<dim3((int)(WS / 1024), 1, 4), 256, 0, stream>>>(wq, wk, wv, wo, wb, (int)WS);

  // fused QKV: z selects weight/bias/output slice; z==2 writes transposed to vT
  gemm256_k<false><<<dim3(DIMC / 256, MTOK / 256, 3), 512, 0, stream>>>(
      xb, wb, bq, bk, bv, qkv, vT, WS, QS, DIMC, DIMC);

  rmsrope_k<<<MTOK, 256, 0, stream>>>(qkv, gq, gk, freqs);
  attn_k<<<dim3(SEQ / 128, BSZ * NH), 256, 0, stream>>>(qkv, qkv + 1 * QS, vT, ob);

  gemm256_k<true><<<dim3(DIMC / 256, MTOK / 256, 1), 512, 0, stream>>>(
      ob, wb + 3 * WS, bo, bo, bo, d_out, nullptr, 0, 0, DIMC, DIMC);
}

// Round 13
// 640.802 us; speedup vs baseline: 1.0287x; 1.0287x over previous
//
#include <hip/hip_runtime.h>
#include <hip/hip_bf16.h>

typedef unsigned short u16;
typedef __bf16 bf16x8 __attribute__((ext_vector_type(8)));
typedef float f32x4 __attribute__((ext_vector_type(4)));
typedef float f32x16 __attribute__((ext_vector_type(16)));

#define DIMC  2048
#define NH    16
#define HD    128
#define BSZ   2
#define SEQ   4096
#define MTOK  (BSZ*SEQ)   /* 8192 tokens */

// scale * log2(e): folded into Q at rmsrope time
#define SCALE_L2E (0.08838834764831845f * 1.4426950408889634f)

__device__ __forceinline__ u16 f2bf(float f) {
  unsigned u = __float_as_uint(f);
  u += 0x7fff + ((u >> 16) & 1);   // RTNE
  return (u16)(u >> 16);
}
__device__ __forceinline__ float bf2f(u16 b) {
  return __uint_as_float(((unsigned)b) << 16);
}

__device__ __forceinline__ void gload_lds16(const void* g, void* l) {
  __builtin_amdgcn_global_load_lds(
      (const __attribute__((address_space(1))) void*)g,
      (__attribute__((address_space(3))) void*)l, 16, 0, 0);
}

#define BAR() __builtin_amdgcn_s_barrier()
#define ASM_VMCNT(n) do { asm volatile("s_waitcnt vmcnt(" #n ")" ::: "memory"); \
                          __builtin_amdgcn_sched_barrier(0); } while (0)
#define ASM_LGK0()   do { asm volatile("s_waitcnt lgkmcnt(0)" ::: "memory");    \
                          __builtin_amdgcn_sched_barrier(0); } while (0)

// ---------------- cast f32 -> bf16 ----------------
__global__ __launch_bounds__(256) void cast_bf16_k(const float* __restrict__ in,
                                                   u16* __restrict__ out, int n) {
  int i = (blockIdx.x * 256 + threadIdx.x) * 4;
  if (i >= n) return;
  float4 v = *(const float4*)(in + i);
  ushort4 o;
  o.x = f2bf(v.x); o.y = f2bf(v.y); o.z = f2bf(v.z); o.w = f2bf(v.w);
  *(ushort4*)(out + i) = o;
}

// cast the 4 weight matrices in one dispatch (z selects the matrix)
__global__ __launch_bounds__(256) void cast_w4_k(
    const float* __restrict__ w0, const float* __restrict__ w1,
    const float* __restrict__ w2, const float* __restrict__ w3,
    u16* __restrict__ out, int n) {
  const int z = blockIdx.z;
  const float* src = (z == 0) ? w0 : (z == 1) ? w1 : (z == 2) ? w2 : w3;
  u16* dst = out + (size_t)z * n;
  int i = (blockIdx.x * 256 + threadIdx.x) * 4;
  if (i >= n) return;
  float4 v = *(const float4*)(src + i);
  ushort4 o;
  o.x = f2bf(v.x); o.y = f2bf(v.y); o.z = f2bf(v.z); o.w = f2bf(v.w);
  *(ushort4*)(dst + i) = o;
}

// ---------------- 256x256 8-phase GEMM (T2+T3+T4+T5) ----------------
// z==2 (the V projection) writes its output DIRECTLY TRANSPOSED to vT via an
// LDS bounce (the 128 KiB As/Bs buffer == one 256x256 bf16 tile exactly).
#define AsBuf(d, h) (SMEM[(d) * 2 + (h)])
#define BsBuf(d, h) (SMEM[4 + (d) * 2 + (h)])

#define STG_A(d, kt, h)                                                        \
  { const u16* s_ = Ag + (size_t)(h) * khalf + (size_t)(kt) * 64;              \
    gload_lds16(s_ + at0, (u16*)AsBuf(d, h) + tid * 8);                        \
    gload_lds16(s_ + at1, (u16*)AsBuf(d, h) + (tid + 512) * 8); }
#define STG_B(d, kt, h)                                                        \
  { const u16* s_ = Bg + (size_t)(h) * khalf + (size_t)(kt) * 64;              \
    gload_lds16(s_ + at0, (u16*)BsBuf(d, h) + tid * 8);                        \
    gload_lds16(s_ + at1, (u16*)BsBuf(d, h) + (tid + 512) * 8); }

#define GPHASE(bb, q, STAGE_CODE, TAIL_CODE)                                   \
  {                                                                            \
    if ((q) == 0) {                                                            \
      _Pragma("unroll") for (int fc = 0; fc < 4; fc++)                         \
        _Pragma("unroll") for (int ks = 0; ks < 2; ks++)                       \
          bfr[fc][ks] = *(const bf16x8*)((const char*)BsBuf(bb, wc >> 1) +     \
              rbB + fc * 2048 + colr[ks]);                                     \
    }                                                                          \
    _Pragma("unroll") for (int e = 0; e < 2; e++)                              \
      _Pragma("unroll") for (int ks = 0; ks < 2; ks++)                         \
        afr[e][ks] = *(const bf16x8*)((const char*)AsBuf(bb, wr) +             \
            rbA + (2 * (q) + e) * 2048 + colr[ks]);                            \
    STAGE_CODE;                                                                \
    BAR();                                                                     \
    ASM_LGK0();                                                                \
    __builtin_amdgcn_s_setprio(1);                                             \
    _Pragma("unroll") for (int e = 0; e < 2; e++)                              \
      _Pragma("unroll") for (int fc = 0; fc < 4; fc++)                         \
        _Pragma("unroll") for (int ks = 0; ks < 2; ks++)                       \
          acc[2 * (q) + e][fc] = __builtin_amdgcn_mfma_f32_16x16x32_bf16(      \
              afr[e][ks], bfr[fc][ks], acc[2 * (q) + e][fc], 0, 0, 0);         \
    __builtin_amdgcn_s_setprio(0);                                             \
    TAIL_CODE;                                                                 \
    BAR();                                                                     \
    __builtin_amdgcn_sched_barrier(0);                                         \
  }

template<bool OUT_F32>
__global__ __launch_bounds__(512, 2) void gemm256_k(
    const u16* __restrict__ A, const u16* __restrict__ Bt,
    const float* __restrict__ b0, const float* __restrict__ b1,
    const float* __restrict__ b2, void* __restrict__ Cout,
    u16* __restrict__ vTout,
    size_t wstride, size_t ostride, int Ndim, int Kdim) {
  __shared__ __align__(16) u16 SMEM[8][128 * 64];
  const int tid = threadIdx.x;
  const int lane = tid & 63, wid = tid >> 6;
  const int wr = wid >> 2, wc = wid & 3;          // 2M x 4N waves
  const int l15 = lane & 15, lg = lane >> 4;
  const int z = blockIdx.z;

  const u16* W = Bt + (size_t)z * wstride;
  const float* bias = (z == 0) ? b0 : (z == 1 ? b1 : b2);

  const int flat = blockIdx.y * gridDim.x + blockIdx.x;
  const int cpx = (gridDim.x * gridDim.y) >> 3;
  const int swz = (flat & 7) * cpx + (flat >> 3);
  const int bn = (swz % gridDim.x) * 256;
  const int bm = (swz / gridDim.x) * 256;

  const u16* Ag = A + (size_t)bm * Kdim;
  const u16* Bg = W + (size_t)bn * Kdim;
  const size_t khalf = (size_t)128 * Kdim;

  const int r0 = tid >> 3, cc0 = tid & 7;
  const size_t at0 = (size_t)r0 * Kdim + (size_t)((cc0 ^ (r0 & 7)) * 8);
  const size_t at1 = at0 + (size_t)64 * Kdim;

  const int swzl = (l15 & 7) << 4;
  int colr[2];
  colr[0] = (0 * 64 + lg * 16) ^ swzl;
  colr[1] = (1 * 64 + lg * 16) ^ swzl;
  const int rbA = l15 * 128;
  const int rbB = (wc & 1) * 8192 + l15 * 128;

  f32x4 acc[8][4];
#pragma unroll
  for (int i = 0; i < 8; i++)
#pragma unroll
    for (int j = 0; j < 4; j++) acc[i][j] = f32x4{0.f, 0.f, 0.f, 0.f};
  bf16x8 bfr[4][2], afr[2][2];

  STG_A(0, 0, 0); STG_A(0, 0, 1);
  STG_B(0, 0, 0); STG_B(0, 0, 1);
  STG_B(1, 1, 0); STG_B(1, 1, 1);
  ASM_VMCNT(4);
  BAR();

  const int niter = Kdim / 128 - 1;
#pragma unroll 1
  for (int k = 0; k < niter; ++k) {
    const int t = 2 * k;
    GPHASE(0, 0, STG_A(1, t + 1, 0), (void)0);
    GPHASE(0, 1, STG_A(1, t + 1, 1), (void)0);
    GPHASE(0, 2, STG_B(0, t + 2, 0), (void)0);
    GPHASE(0, 3, STG_B(0, t + 2, 1), ASM_VMCNT(4));
    GPHASE(1, 0, STG_A(0, t + 2, 0), (void)0);
    GPHASE(1, 1, STG_A(0, t + 2, 1), (void)0);
    GPHASE(1, 2, STG_B(1, t + 3, 0), (void)0);
    GPHASE(1, 3, STG_B(1, t + 3, 1), ASM_VMCNT(4));
  }
  {
    const int tl = Kdim / 64 - 1;
    GPHASE(0, 0, STG_A(1, tl, 0), (void)0);
    GPHASE(0, 1, STG_A(1, tl, 1), (void)0);
    GPHASE(0, 2, (void)0, (void)0);
    GPHASE(0, 3, (void)0, ASM_VMCNT(0));
    GPHASE(1, 0, (void)0, (void)0);
    GPHASE(1, 1, (void)0, (void)0);
    GPHASE(1, 2, (void)0, (void)0);
    GPHASE(1, 3, (void)0, (void)0);
  }

  if (!OUT_F32 && z == 2) {
    // transposed write of the V projection via LDS bounce.
    u16* Ts = &SMEM[0][0];
#pragma unroll
    for (int fc = 0; fc < 4; fc++) {
      const int ch = wc * 64 + fc * 16 + l15;
      const float bv = bias[bn + ch];
      const int chx = (ch & 31) << 4;
#pragma unroll
      for (int fr = 0; fr < 8; fr++) {
        const int tok2 = (wr * 128 + fr * 16 + lg * 4) * 2;
        ushort4 w;
        w.x = f2bf(acc[fr][fc][0] + bv);
        w.y = f2bf(acc[fr][fc][1] + bv);
        w.z = f2bf(acc[fr][fc][2] + bv);
        w.w = f2bf(acc[fr][fc][3] + bv);
        *(ushort4*)((char*)Ts + ch * 512 + (tok2 ^ chx)) = w;
      }
    }
    __syncthreads();
    const int b_ = bm >> 12, sm = bm & (SEQ - 1);
    const int l5 = tid & 31, g5 = tid >> 5;     // 16 groups of 32 lanes
#pragma unroll
    for (int i = 0; i < 16; i++) {
      const int ch = i * 16 + g5;
      const uint4 dv = *(const uint4*)((const char*)Ts + ch * 512 +
                                       ((l5 * 16) ^ ((ch & 31) << 4)));
      *(uint4*)(vTout + (size_t)(b_ * DIMC + bn + ch) * SEQ + sm + l5 * 8) = dv;
    }
  } else {
#pragma unroll
    for (int fc = 0; fc < 4; fc++) {
      const int cj = bn + wc * 64 + fc * 16 + l15;
      const float bv = bias[cj];
#pragma unroll
      for (int fr = 0; fr < 8; fr++) {
        const int row0 = bm + wr * 128 + fr * 16 + lg * 4;
#pragma unroll
        for (int r = 0; r < 4; r++) {
          float v = acc[fr][fc][r] + bv;
          if (OUT_F32)
            ((float*)Cout)[(size_t)z * ostride + (size_t)(row0 + r) * Ndim + cj] = v;
          else
            ((u16*)Cout)[(size_t)z * ostride + (size_t)(row0 + r) * Ndim + cj] = f2bf(v);
        }
      }
    }
  }
}

// ---------------- fused RMSNorm + RoPE (in-place on q,k; bf16 storage) ----------------
__global__ __launch_bounds__(256) void rmsrope_k(
    u16* __restrict__ qk, const float* __restrict__ gq, const float* __restrict__ gk,
    const float* __restrict__ freqs) {
  const int t = blockIdx.x;        // token
  const int s = t & (SEQ - 1);
  const int tid = threadIdx.x;
  __shared__ float red[8];

  for (int which = 0; which < 2; ++which) {
    u16* row = qk + (size_t)which * ((size_t)MTOK * DIMC) + (size_t)t * DIMC;
    const float* g = which ? gk : gq;
    const float oscale = which ? 1.0f : SCALE_L2E;
    uint4 raw = *(const uint4*)(row + tid * 8);
    const u16* rb = (const u16*)&raw;
    float v[8], ss = 0.f;
#pragma unroll
    for (int e = 0; e < 8; e++) { v[e] = bf2f(rb[e]); ss += v[e] * v[e]; }
#pragma unroll
    for (int m = 1; m < 64; m <<= 1) ss += __shfl_xor(ss, m);
    if ((tid & 63) == 0) red[which * 4 + (tid >> 6)] = ss;
    __syncthreads();
    float tot = red[which * 4] + red[which * 4 + 1] + red[which * 4 + 2] + red[which * 4 + 3];
    float rms = rsqrtf(tot * (1.0f / (float)DIMC) + 1e-6f);
    const int ch0 = tid * 8;
    const int d0 = ch0 & (HD - 1);
    u16 ob[8];
#pragma unroll
    for (int p = 0; p < 4; p++) {
      float fr = freqs[s * (HD / 2) + (d0 >> 1) + p];
      float cs = cosf(fr), sn = sinf(fr);
      float e = v[2 * p] * rms * g[ch0 + 2 * p];
      float o = v[2 * p + 1] * rms * g[ch0 + 2 * p + 1];
      ob[2 * p]     = f2bf((e * cs - o * sn) * oscale);
      ob[2 * p + 1] = f2bf((e * sn + o * cs) * oscale);
    }
    *(uint4*)(row + tid * 8) = *(const uint4*)ob;
    __syncthreads();
  }
}

// ---------------- flash attention: 32x32 swapped-QK^T, in-register softmax ----
// R10 structure (proven 354us): 8 waves x 32 q = 256 q/block, K/V double-
// buffered, STAGE(t+1) before COMPUTE(t), 1 barrier/tile. This round: T5
// s_setprio(1/0) around the QK^T and PV MFMA clusters (m191 attn recipe).
#define STAGE(KS, VS, kv0)                                                     \
  _Pragma("unroll") for (int it = 0; it < 2; ++it) {                           \
    const int c = it * 512 + tid;                                              \
    { const int rr = c >> 4, ss = c & 15;                                      \
      gload_lds16(Kp + (size_t)((kv0) + rr) * DIMC + ((ss ^ (rr & 15)) * 8),   \
                  (u16*)(KS) + c * 8); }                                       \
    { const int rr = c >> 3, ss = c & 7;                                       \
      gload_lds16(Vp + (size_t)rr * SEQ + (kv0) + ((ss ^ (rr & 7)) * 8),       \
                  (u16*)(VS) + c * 8); }                                       \
  }

#define CROW(r) (((r) & 3) + 8 * ((r) >> 2) + 4 * hi)

#define COMPUTE(KS, VS)                                                        \
  {                                                                            \
    f32x16 s0, s1;                                                             \
    _Pragma("unroll") for (int i = 0; i < 16; i++) { s0[i] = 0.f; s1[i] = 0.f; } \
    __builtin_amdgcn_s_setprio(1);                                             \
    _Pragma("unroll") for (int j = 0; j < 8; ++j) {                            \
      const int byt = (j * 32 + hi * 16);                                      \
      const bf16x8 k0 = *(const bf16x8*)((const char*)(KS) + l31 * 256 +       \
                        (byt ^ ((l31 & 15) << 4)));                            \
      const bf16x8 k1 = *(const bf16x8*)((const char*)(KS) + (32 + l31) * 256 + \
                        (byt ^ ((l31 & 15) << 4)));                            \
      s0 = __builtin_amdgcn_mfma_f32_32x32x16_bf16(k0, qf[j], s0, 0, 0, 0);    \
      s1 = __builtin_amdgcn_mfma_f32_32x32x16_bf16(k1, qf[j], s1, 0, 0, 0);    \
    }                                                                          \
    __builtin_amdgcn_s_setprio(0);                                             \
    float mt[16];                                                              \
    _Pragma("unroll") for (int r = 0; r < 16; r++) mt[r] = fmaxf(s0[r], s1[r]); \
    _Pragma("unroll") for (int st = 8; st > 0; st >>= 1)                       \
      _Pragma("unroll") for (int r = 0; r < st; r++) mt[r] = fmaxf(mt[r], mt[r + st]); \
    float rmax = fmaxf(mt[0], __shfl_xor(mt[0], 32));                          \
    if (!__all(rmax - mq <= 8.0f)) {                                           \
      const float mn = fmaxf(mq, rmax);                                        \
      const float al = exp2f(mq - mn);                                         \
      mq = mn; lq *= al;                                                       \
      _Pragma("unroll") for (int r = 0; r < 16; r++) {                         \
        const float ar = __shfl(al, CROW(r));                                  \
        _Pragma("unroll") for (int d = 0; d < 4; d++) accO[d][r] *= ar;        \
      }                                                                        \
    }                                                                          \
    float p[32]; float rsum = 0.f;                                             \
    _Pragma("unroll") for (int r = 0; r < 16; r++) {                           \
      p[r] = exp2f(s0[r] - mq); rsum += p[r];                                  \
      p[16 + r] = exp2f(s1[r] - mq); rsum += p[16 + r];                        \
    }                                                                          \
    rsum += __shfl_xor(rsum, 32);                                              \
    lq += rsum;                                                                \
    bf16x8 pa[4];                                                              \
    _Pragma("unroll") for (int kb = 0; kb < 2; kb++) {                         \
      unsigned A0, A1, A2, A3, A4, A5, A6, A7;                                 \
      const int bp = kb * 16;                                                  \
      asm("v_cvt_pk_bf16_f32 %0, %1, %2" : "=v"(A0) : "v"(p[bp+0]), "v"(p[bp+1])); \
      asm("v_cvt_pk_bf16_f32 %0, %1, %2" : "=v"(A1) : "v"(p[bp+2]), "v"(p[bp+3])); \
      asm("v_cvt_pk_bf16_f32 %0, %1, %2" : "=v"(A2) : "v"(p[bp+4]), "v"(p[bp+5])); \
      asm("v_cvt_pk_bf16_f32 %0, %1, %2" : "=v"(A3) : "v"(p[bp+6]), "v"(p[bp+7])); \
      asm("v_cvt_pk_bf16_f32 %0, %1, %2" : "=v"(A4) : "v"(p[bp+8]), "v"(p[bp+9])); \
      asm("v_cvt_pk_bf16_f32 %0, %1, %2" : "=v"(A5) : "v"(p[bp+10]), "v"(p[bp+11])); \
      asm("v_cvt_pk_bf16_f32 %0, %1, %2" : "=v"(A6) : "v"(p[bp+12]), "v"(p[bp+13])); \
      asm("v_cvt_pk_bf16_f32 %0, %1, %2" : "=v"(A7) : "v"(p[bp+14]), "v"(p[bp+15])); \
      asm("v_permlane32_swap_b32 %0, %1" : "+v"(A0), "+v"(A2));                \
      asm("v_permlane32_swap_b32 %0, %1" : "+v"(A1), "+v"(A3));                \
      asm("v_permlane32_swap_b32 %0, %1" : "+v"(A4), "+v"(A6));                \
      asm("v_permlane32_swap_b32 %0, %1" : "+v"(A5), "+v"(A7));                \
      union { unsigned u[4]; bf16x8 v; } f0, f1;                               \
      f0.u[0] = A0; f0.u[1] = A1; f0.u[2] = A2; f0.u[3] = A3;                  \
      f1.u[0] = A4; f1.u[1] = A5; f1.u[2] = A6; f1.u[3] = A7;                  \
      pa[kb * 2] = f0.v; pa[kb * 2 + 1] = f1.v;                                \
    }                                                                          \
    __builtin_amdgcn_s_setprio(1);                                             \
    _Pragma("unroll") for (int c = 0; c < 4; c++) {                            \
      _Pragma("unroll") for (int d = 0; d < 4; d++) {                          \
        const int vrow = d * 32 + l31;                                         \
        const bf16x8 vb = *(const bf16x8*)((const char*)(VS) + vrow * 128 +    \
                          ((c * 32 + hi * 16) ^ ((vrow & 7) << 4)));           \
        accO[d] = __builtin_amdgcn_mfma_f32_32x32x16_bf16(pa[c], vb, accO[d], 0, 0, 0); \
      }                                                                        \
    }                                                                          \
    __builtin_amdgcn_s_setprio(0);                                             \
  }

__global__ __launch_bounds__(512, 2) void attn_k(
    const u16* __restrict__ qbuf, const u16* __restrict__ kbuf,
    const u16* __restrict__ vT, u16* __restrict__ obuf) {
  const int flat = blockIdx.y * gridDim.x + blockIdx.x;   // 512 total
  const int swz = (flat & 7) * 64 + (flat >> 3);          // XCD chunks of 64
  const int bh = swz >> 4, b = bh >> 4, h = bh & 15;
  const int q0 = (swz & 15) * 256;
  const int tid = threadIdx.x, lane = tid & 63, wid = tid >> 6;
  const int l31 = lane & 31, hi = lane >> 5;

  __shared__ __align__(16) u16 Ks0[64 * 128];
  __shared__ __align__(16) u16 Ks1[64 * 128];
  __shared__ __align__(16) u16 Vs0[128 * 64];
  __shared__ __align__(16) u16 Vs1[128 * 64];

  const size_t qkbase = (size_t)(b * SEQ) * DIMC + h * HD;
  const u16* Qp = qbuf + qkbase;
  const u16* Kp = kbuf + qkbase;
  const u16* Vp = vT + (size_t)(b * DIMC + h * HD) * SEQ;

  bf16x8 qf[8];
  const int qrow = q0 + wid * 32 + l31;
#pragma unroll
  for (int j = 0; j < 8; ++j)
    qf[j] = *(const bf16x8*)(Qp + (size_t)qrow * DIMC + j * 16 + hi * 8);

  float mq = -1e30f, lq = 0.f;
  f32x16 accO[4];
#pragma unroll
  for (int d = 0; d < 4; d++)
#pragma unroll
    for (int i = 0; i < 16; i++) accO[d][i] = 0.f;

  STAGE(Ks0, Vs0, 0);
  __syncthreads();

#pragma unroll 1
  for (int t = 0; t < SEQ / 64; t += 2) {
    STAGE(Ks1, Vs1, (t + 1) * 64);
    COMPUTE(Ks0, Vs0);
    __syncthreads();
    if (t + 2 < SEQ / 64) STAGE(Ks0, Vs0, (t + 2) * 64);
    COMPUTE(Ks1, Vs1);
    __syncthreads();
  }

  const float linv = 1.0f / lq;
  u16* Op = obuf + (size_t)(b * SEQ + q0 + wid * 32) * DIMC + h * HD;
#pragma unroll
  for (int r = 0; r < 16; r++) {
    const float lr = __shfl(linv, CROW(r));
    const int orow = CROW(r);
#pragma unroll
    for (int d = 0; d < 4; d++)
      Op[(size_t)orow * DIMC + d * 32 + l31] = f2bf(accO[d][r] * lr);
  }
}

// ---------------- launch ----------------
extern "C" void kernel_launch(void* const* d_in, const int* in_sizes, int n_in,
                              void* d_out, int out_size, void* d_ws, size_t ws_size,
                              hipStream_t stream) {
  const float* x     = (const float*)d_in[0];
  const float* freqs = (const float*)d_in[2];
  const float* wq = (const float*)d_in[3];
  const float* bq = (const float*)d_in[4];
  const float* wk = (const float*)d_in[5];
  const float* bk = (const float*)d_in[6];
  const float* wv = (const float*)d_in[7];
  const float* bv = (const float*)d_in[8];
  const float* wo = (const float*)d_in[9];
  const float* bo = (const float*)d_in[10];
  const float* gq = (const float*)d_in[11];
  const float* gk = (const float*)d_in[12];

  const size_t WS = (size_t)DIMC * DIMC;       // weight elems
  const size_t QS = (size_t)MTOK * DIMC;       // activation elems
  char* ws = (char*)d_ws;
  u16* xb  = (u16*)ws;  ws += QS * 2;
  u16* wb  = (u16*)ws;  ws += 4 * WS * 2;
  u16* qkv = (u16*)ws;  ws += 3 * QS * 2;
  u16* vT  = (u16*)ws;  ws += QS * 2;
  u16* ob  = (u16*)ws;  ws += QS * 2;

  cast_bf16_k<<<(int)(QS / 1024), 256, 0, stream>>>(x, xb, (int)QS);
  cast_w4_k<<<dim3((int)(WS / 1024), 1, 4), 256, 0, stream>>>(wq, wk, wv, wo, wb, (int)WS);

  // fused QKV: z selects weight/bias/output slice; z==2 writes transposed to vT
  gemm256_k<false><<<dim3(DIMC / 256, MTOK / 256, 3), 512, 0, stream>>>(
      xb, wb, bq, bk, bv, qkv, vT, WS, QS, DIMC, DIMC);

  rmsrope_k<<<MTOK, 256, 0, stream>>>(qkv, gq, gk, freqs);
  attn_k<<<dim3(SEQ / 256, BSZ * NH), 512, 0, stream>>>(qkv, qkv + 1 * QS, vT, ob);

  gemm256_k<true><<<dim3(DIMC / 256, MTOK / 256, 1), 512, 0, stream>>>(
      ob, wb + 3 * WS, bo, bo, bo, d_out, nullptr, 0, 0, DIMC, DIMC);
}

// Round 14
// 633.065 us; speedup vs baseline: 1.0412x; 1.0122x over previous
//
#include <hip/hip_runtime.h>
#include <hip/hip_bf16.h>

typedef unsigned short u16;
typedef __bf16 bf16x8 __attribute__((ext_vector_type(8)));
typedef float f32x4 __attribute__((ext_vector_type(4)));
typedef float f32x16 __attribute__((ext_vector_type(16)));

#define DIMC  2048
#define NH    16
#define HD    128
#define BSZ   2
#define SEQ   4096
#define MTOK  (BSZ*SEQ)   /* 8192 tokens */

// scale * log2(e): folded into Q at rmsrope time
#define SCALE_L2E (0.08838834764831845f * 1.4426950408889634f)

__device__ __forceinline__ u16 f2bf(float f) {
  unsigned u = __float_as_uint(f);
  u += 0x7fff + ((u >> 16) & 1);   // RTNE
  return (u16)(u >> 16);
}
__device__ __forceinline__ float bf2f(u16 b) {
  return __uint_as_float(((unsigned)b) << 16);
}

__device__ __forceinline__ void gload_lds16(const void* g, void* l) {
  __builtin_amdgcn_global_load_lds(
      (const __attribute__((address_space(1))) void*)g,
      (__attribute__((address_space(3))) void*)l, 16, 0, 0);
}

#define BAR() __builtin_amdgcn_s_barrier()
#define ASM_VMCNT(n) do { asm volatile("s_waitcnt vmcnt(" #n ")" ::: "memory"); \
                          __builtin_amdgcn_sched_barrier(0); } while (0)
#define ASM_LGK0()   do { asm volatile("s_waitcnt lgkmcnt(0)" ::: "memory");    \
                          __builtin_amdgcn_sched_barrier(0); } while (0)

// ---------------- cast f32 -> bf16 ----------------
__global__ __launch_bounds__(256) void cast_bf16_k(const float* __restrict__ in,
                                                   u16* __restrict__ out, int n) {
  int i = (blockIdx.x * 256 + threadIdx.x) * 4;
  if (i >= n) return;
  float4 v = *(const float4*)(in + i);
  ushort4 o;
  o.x = f2bf(v.x); o.y = f2bf(v.y); o.z = f2bf(v.z); o.w = f2bf(v.w);
  *(ushort4*)(out + i) = o;
}

// cast the 4 weight matrices in one dispatch (z selects the matrix)
__global__ __launch_bounds__(256) void cast_w4_k(
    const float* __restrict__ w0, const float* __restrict__ w1,
    const float* __restrict__ w2, const float* __restrict__ w3,
    u16* __restrict__ out, int n) {
  const int z = blockIdx.z;
  const float* src = (z == 0) ? w0 : (z == 1) ? w1 : (z == 2) ? w2 : w3;
  u16* dst = out + (size_t)z * n;
  int i = (blockIdx.x * 256 + threadIdx.x) * 4;
  if (i >= n) return;
  float4 v = *(const float4*)(src + i);
  ushort4 o;
  o.x = f2bf(v.x); o.y = f2bf(v.y); o.z = f2bf(v.z); o.w = f2bf(v.w);
  *(ushort4*)(dst + i) = o;
}

// ---------------- 256x256 8-phase GEMM (T2+T3+T4+T5) ----------------
// z==2 (the V projection) writes its output DIRECTLY TRANSPOSED to vT via an
// LDS bounce (the 128 KiB As/Bs buffer == one 256x256 bf16 tile exactly).
#define AsBuf(d, h) (SMEM[(d) * 2 + (h)])
#define BsBuf(d, h) (SMEM[4 + (d) * 2 + (h)])

#define STG_A(d, kt, h)                                                        \
  { const u16* s_ = Ag + (size_t)(h) * khalf + (size_t)(kt) * 64;              \
    gload_lds16(s_ + at0, (u16*)AsBuf(d, h) + tid * 8);                        \
    gload_lds16(s_ + at1, (u16*)AsBuf(d, h) + (tid + 512) * 8); }
#define STG_B(d, kt, h)                                                        \
  { const u16* s_ = Bg + (size_t)(h) * khalf + (size_t)(kt) * 64;              \
    gload_lds16(s_ + at0, (u16*)BsBuf(d, h) + tid * 8);                        \
    gload_lds16(s_ + at1, (u16*)BsBuf(d, h) + (tid + 512) * 8); }

#define GPHASE(bb, q, STAGE_CODE, TAIL_CODE)                                   \
  {                                                                            \
    if ((q) == 0) {                                                            \
      _Pragma("unroll") for (int fc = 0; fc < 4; fc++)                         \
        _Pragma("unroll") for (int ks = 0; ks < 2; ks++)                       \
          bfr[fc][ks] = *(const bf16x8*)((const char*)BsBuf(bb, wc >> 1) +     \
              rbB + fc * 2048 + colr[ks]);                                     \
    }                                                                          \
    _Pragma("unroll") for (int e = 0; e < 2; e++)                              \
      _Pragma("unroll") for (int ks = 0; ks < 2; ks++)                         \
        afr[e][ks] = *(const bf16x8*)((const char*)AsBuf(bb, wr) +             \
            rbA + (2 * (q) + e) * 2048 + colr[ks]);                            \
    STAGE_CODE;                                                                \
    BAR();                                                                     \
    ASM_LGK0();                                                                \
    __builtin_amdgcn_s_setprio(1);                                             \
    _Pragma("unroll") for (int e = 0; e < 2; e++)                              \
      _Pragma("unroll") for (int fc = 0; fc < 4; fc++)                         \
        _Pragma("unroll") for (int ks = 0; ks < 2; ks++)                       \
          acc[2 * (q) + e][fc] = __builtin_amdgcn_mfma_f32_16x16x32_bf16(      \
              afr[e][ks], bfr[fc][ks], acc[2 * (q) + e][fc], 0, 0, 0);         \
    __builtin_amdgcn_s_setprio(0);                                             \
    TAIL_CODE;                                                                 \
    BAR();                                                                     \
    __builtin_amdgcn_sched_barrier(0);                                         \
  }

template<bool OUT_F32>
__global__ __launch_bounds__(512, 2) void gemm256_k(
    const u16* __restrict__ A, const u16* __restrict__ Bt,
    const float* __restrict__ b0, const float* __restrict__ b1,
    const float* __restrict__ b2, void* __restrict__ Cout,
    u16* __restrict__ vTout,
    size_t wstride, size_t ostride, int Ndim, int Kdim) {
  __shared__ __align__(16) u16 SMEM[8][128 * 64];
  const int tid = threadIdx.x;
  const int lane = tid & 63, wid = tid >> 6;
  const int wr = wid >> 2, wc = wid & 3;          // 2M x 4N waves
  const int l15 = lane & 15, lg = lane >> 4;
  const int z = blockIdx.z;

  const u16* W = Bt + (size_t)z * wstride;
  const float* bias = (z == 0) ? b0 : (z == 1 ? b1 : b2);

  const int flat = blockIdx.y * gridDim.x + blockIdx.x;
  const int cpx = (gridDim.x * gridDim.y) >> 3;
  const int swz = (flat & 7) * cpx + (flat >> 3);
  const int bn = (swz % gridDim.x) * 256;
  const int bm = (swz / gridDim.x) * 256;

  const u16* Ag = A + (size_t)bm * Kdim;
  const u16* Bg = W + (size_t)bn * Kdim;
  const size_t khalf = (size_t)128 * Kdim;

  const int r0 = tid >> 3, cc0 = tid & 7;
  const size_t at0 = (size_t)r0 * Kdim + (size_t)((cc0 ^ (r0 & 7)) * 8);
  const size_t at1 = at0 + (size_t)64 * Kdim;

  const int swzl = (l15 & 7) << 4;
  int colr[2];
  colr[0] = (0 * 64 + lg * 16) ^ swzl;
  colr[1] = (1 * 64 + lg * 16) ^ swzl;
  const int rbA = l15 * 128;
  const int rbB = (wc & 1) * 8192 + l15 * 128;

  f32x4 acc[8][4];
#pragma unroll
  for (int i = 0; i < 8; i++)
#pragma unroll
    for (int j = 0; j < 4; j++) acc[i][j] = f32x4{0.f, 0.f, 0.f, 0.f};
  bf16x8 bfr[4][2], afr[2][2];

  STG_A(0, 0, 0); STG_A(0, 0, 1);
  STG_B(0, 0, 0); STG_B(0, 0, 1);
  STG_B(1, 1, 0); STG_B(1, 1, 1);
  ASM_VMCNT(4);
  BAR();

  const int niter = Kdim / 128 - 1;
#pragma unroll 1
  for (int k = 0; k < niter; ++k) {
    const int t = 2 * k;
    GPHASE(0, 0, STG_A(1, t + 1, 0), (void)0);
    GPHASE(0, 1, STG_A(1, t + 1, 1), (void)0);
    GPHASE(0, 2, STG_B(0, t + 2, 0), (void)0);
    GPHASE(0, 3, STG_B(0, t + 2, 1), ASM_VMCNT(4));
    GPHASE(1, 0, STG_A(0, t + 2, 0), (void)0);
    GPHASE(1, 1, STG_A(0, t + 2, 1), (void)0);
    GPHASE(1, 2, STG_B(1, t + 3, 0), (void)0);
    GPHASE(1, 3, STG_B(1, t + 3, 1), ASM_VMCNT(4));
  }
  {
    const int tl = Kdim / 64 - 1;
    GPHASE(0, 0, STG_A(1, tl, 0), (void)0);
    GPHASE(0, 1, STG_A(1, tl, 1), (void)0);
    GPHASE(0, 2, (void)0, (void)0);
    GPHASE(0, 3, (void)0, ASM_VMCNT(0));
    GPHASE(1, 0, (void)0, (void)0);
    GPHASE(1, 1, (void)0, (void)0);
    GPHASE(1, 2, (void)0, (void)0);
    GPHASE(1, 3, (void)0, (void)0);
  }

  if (!OUT_F32 && z == 2) {
    // transposed write of the V projection via LDS bounce.
    u16* Ts = &SMEM[0][0];
#pragma unroll
    for (int fc = 0; fc < 4; fc++) {
      const int ch = wc * 64 + fc * 16 + l15;
      const float bv = bias[bn + ch];
      const int chx = (ch & 31) << 4;
#pragma unroll
      for (int fr = 0; fr < 8; fr++) {
        const int tok2 = (wr * 128 + fr * 16 + lg * 4) * 2;
        ushort4 w;
        w.x = f2bf(acc[fr][fc][0] + bv);
        w.y = f2bf(acc[fr][fc][1] + bv);
        w.z = f2bf(acc[fr][fc][2] + bv);
        w.w = f2bf(acc[fr][fc][3] + bv);
        *(ushort4*)((char*)Ts + ch * 512 + (tok2 ^ chx)) = w;
      }
    }
    __syncthreads();
    const int b_ = bm >> 12, sm = bm & (SEQ - 1);
    const int l5 = tid & 31, g5 = tid >> 5;     // 16 groups of 32 lanes
#pragma unroll
    for (int i = 0; i < 16; i++) {
      const int ch = i * 16 + g5;
      const uint4 dv = *(const uint4*)((const char*)Ts + ch * 512 +
                                       ((l5 * 16) ^ ((ch & 31) << 4)));
      *(uint4*)(vTout + (size_t)(b_ * DIMC + bn + ch) * SEQ + sm + l5 * 8) = dv;
    }
  } else {
#pragma unroll
    for (int fc = 0; fc < 4; fc++) {
      const int cj = bn + wc * 64 + fc * 16 + l15;
      const float bv = bias[cj];
#pragma unroll
      for (int fr = 0; fr < 8; fr++) {
        const int row0 = bm + wr * 128 + fr * 16 + lg * 4;
#pragma unroll
        for (int r = 0; r < 4; r++) {
          float v = acc[fr][fc][r] + bv;
          if (OUT_F32)
            ((float*)Cout)[(size_t)z * ostride + (size_t)(row0 + r) * Ndim + cj] = v;
          else
            ((u16*)Cout)[(size_t)z * ostride + (size_t)(row0 + r) * Ndim + cj] = f2bf(v);
        }
      }
    }
  }
}

// ---------------- fused RMSNorm + RoPE (in-place on q,k; bf16 storage) ----------------
__global__ __launch_bounds__(256) void rmsrope_k(
    u16* __restrict__ qk, const float* __restrict__ gq, const float* __restrict__ gk,
    const float* __restrict__ freqs) {
  const int t = blockIdx.x;        // token
  const int s = t & (SEQ - 1);
  const int tid = threadIdx.x;
  __shared__ float red[8];

  for (int which = 0; which < 2; ++which) {
    u16* row = qk + (size_t)which * ((size_t)MTOK * DIMC) + (size_t)t * DIMC;
    const float* g = which ? gk : gq;
    const float oscale = which ? 1.0f : SCALE_L2E;
    uint4 raw = *(const uint4*)(row + tid * 8);
    const u16* rb = (const u16*)&raw;
    float v[8], ss = 0.f;
#pragma unroll
    for (int e = 0; e < 8; e++) { v[e] = bf2f(rb[e]); ss += v[e] * v[e]; }
#pragma unroll
    for (int m = 1; m < 64; m <<= 1) ss += __shfl_xor(ss, m);
    if ((tid & 63) == 0) red[which * 4 + (tid >> 6)] = ss;
    __syncthreads();
    float tot = red[which * 4] + red[which * 4 + 1] + red[which * 4 + 2] + red[which * 4 + 3];
    float rms = rsqrtf(tot * (1.0f / (float)DIMC) + 1e-6f);
    const int ch0 = tid * 8;
    const int d0 = ch0 & (HD - 1);
    u16 ob[8];
#pragma unroll
    for (int p = 0; p < 4; p++) {
      float fr = freqs[s * (HD / 2) + (d0 >> 1) + p];
      float cs = cosf(fr), sn = sinf(fr);
      float e = v[2 * p] * rms * g[ch0 + 2 * p];
      float o = v[2 * p + 1] * rms * g[ch0 + 2 * p + 1];
      ob[2 * p]     = f2bf((e * cs - o * sn) * oscale);
      ob[2 * p + 1] = f2bf((e * sn + o * cs) * oscale);
    }
    *(uint4*)(row + tid * 8) = *(const uint4*)ob;
    __syncthreads();
  }
}

// ---------------- flash attention: 32x32 swapped-QK^T, in-register softmax ----
// R10 structure (proven 354us / 633us total): 8 waves x 32 q = 256 q/block,
// K/V double-buffered, STAGE(t+1) issued BEFORE COMPUTE(t), 1 barrier/tile.
// Seven structural variants (occupancy 2/3/4 waves-SIMD, V-from-L2, T15
// pipeline, VALU-diet, T5 setprio) all land 354-377us: SIMD issue port is
// saturated (MfmaUtil+VALUBusy ~95%) -> structural floor for this decomp.
#define STAGE(KS, VS, kv0)                                                     \
  _Pragma("unroll") for (int it = 0; it < 2; ++it) {                           \
    const int c = it * 512 + tid;                                              \
    { const int rr = c >> 4, ss = c & 15;                                      \
      gload_lds16(Kp + (size_t)((kv0) + rr) * DIMC + ((ss ^ (rr & 15)) * 8),   \
                  (u16*)(KS) + c * 8); }                                       \
    { const int rr = c >> 3, ss = c & 7;                                       \
      gload_lds16(Vp + (size_t)rr * SEQ + (kv0) + ((ss ^ (rr & 7)) * 8),       \
                  (u16*)(VS) + c * 8); }                                       \
  }

#define CROW(r) (((r) & 3) + 8 * ((r) >> 2) + 4 * hi)

#define COMPUTE(KS, VS)                                                        \
  {                                                                            \
    f32x16 s0, s1;                                                             \
    _Pragma("unroll") for (int i = 0; i < 16; i++) { s0[i] = 0.f; s1[i] = 0.f; } \
    _Pragma("unroll") for (int j = 0; j < 8; ++j) {                            \
      const int byt = (j * 32 + hi * 16);                                      \
      const bf16x8 k0 = *(const bf16x8*)((const char*)(KS) + l31 * 256 +       \
                        (byt ^ ((l31 & 15) << 4)));                            \
      const bf16x8 k1 = *(const bf16x8*)((const char*)(KS) + (32 + l31) * 256 + \
                        (byt ^ ((l31 & 15) << 4)));                            \
      s0 = __builtin_amdgcn_mfma_f32_32x32x16_bf16(k0, qf[j], s0, 0, 0, 0);    \
      s1 = __builtin_amdgcn_mfma_f32_32x32x16_bf16(k1, qf[j], s1, 0, 0, 0);    \
    }                                                                          \
    float mt[16];                                                              \
    _Pragma("unroll") for (int r = 0; r < 16; r++) mt[r] = fmaxf(s0[r], s1[r]); \
    _Pragma("unroll") for (int st = 8; st > 0; st >>= 1)                       \
      _Pragma("unroll") for (int r = 0; r < st; r++) mt[r] = fmaxf(mt[r], mt[r + st]); \
    float rmax = fmaxf(mt[0], __shfl_xor(mt[0], 32));                          \
    if (!__all(rmax - mq <= 8.0f)) {                                           \
      const float mn = fmaxf(mq, rmax);                                        \
      const float al = exp2f(mq - mn);                                         \
      mq = mn; lq *= al;                                                       \
      _Pragma("unroll") for (int r = 0; r < 16; r++) {                         \
        const float ar = __shfl(al, CROW(r));                                  \
        _Pragma("unroll") for (int d = 0; d < 4; d++) accO[d][r] *= ar;        \
      }                                                                        \
    }                                                                          \
    float p[32]; float rsum = 0.f;                                             \
    _Pragma("unroll") for (int r = 0; r < 16; r++) {                           \
      p[r] = exp2f(s0[r] - mq); rsum += p[r];                                  \
      p[16 + r] = exp2f(s1[r] - mq); rsum += p[16 + r];                        \
    }                                                                          \
    rsum += __shfl_xor(rsum, 32);                                              \
    lq += rsum;                                                                \
    bf16x8 pa[4];                                                              \
    _Pragma("unroll") for (int kb = 0; kb < 2; kb++) {                         \
      unsigned A0, A1, A2, A3, A4, A5, A6, A7;                                 \
      const int bp = kb * 16;                                                  \
      asm("v_cvt_pk_bf16_f32 %0, %1, %2" : "=v"(A0) : "v"(p[bp+0]), "v"(p[bp+1])); \
      asm("v_cvt_pk_bf16_f32 %0, %1, %2" : "=v"(A1) : "v"(p[bp+2]), "v"(p[bp+3])); \
      asm("v_cvt_pk_bf16_f32 %0, %1, %2" : "=v"(A2) : "v"(p[bp+4]), "v"(p[bp+5])); \
      asm("v_cvt_pk_bf16_f32 %0, %1, %2" : "=v"(A3) : "v"(p[bp+6]), "v"(p[bp+7])); \
      asm("v_cvt_pk_bf16_f32 %0, %1, %2" : "=v"(A4) : "v"(p[bp+8]), "v"(p[bp+9])); \
      asm("v_cvt_pk_bf16_f32 %0, %1, %2" : "=v"(A5) : "v"(p[bp+10]), "v"(p[bp+11])); \
      asm("v_cvt_pk_bf16_f32 %0, %1, %2" : "=v"(A6) : "v"(p[bp+12]), "v"(p[bp+13])); \
      asm("v_cvt_pk_bf16_f32 %0, %1, %2" : "=v"(A7) : "v"(p[bp+14]), "v"(p[bp+15])); \
      asm("v_permlane32_swap_b32 %0, %1" : "+v"(A0), "+v"(A2));                \
      asm("v_permlane32_swap_b32 %0, %1" : "+v"(A1), "+v"(A3));                \
      asm("v_permlane32_swap_b32 %0, %1" : "+v"(A4), "+v"(A6));                \
      asm("v_permlane32_swap_b32 %0, %1" : "+v"(A5), "+v"(A7));                \
      union { unsigned u[4]; bf16x8 v; } f0, f1;                               \
      f0.u[0] = A0; f0.u[1] = A1; f0.u[2] = A2; f0.u[3] = A3;                  \
      f1.u[0] = A4; f1.u[1] = A5; f1.u[2] = A6; f1.u[3] = A7;                  \
      pa[kb * 2] = f0.v; pa[kb * 2 + 1] = f1.v;                                \
    }                                                                          \
    _Pragma("unroll") for (int c = 0; c < 4; c++) {                            \
      _Pragma("unroll") for (int d = 0; d < 4; d++) {                          \
        const int vrow = d * 32 + l31;                                         \
        const bf16x8 vb = *(const bf16x8*)((const char*)(VS) + vrow * 128 +    \
                          ((c * 32 + hi * 16) ^ ((vrow & 7) << 4)));           \
        accO[d] = __builtin_amdgcn_mfma_f32_32x32x16_bf16(pa[c], vb, accO[d], 0, 0, 0); \
      }                                                                        \
    }                                                                          \
  }

__global__ __launch_bounds__(512, 2) void attn_k(
    const u16* __restrict__ qbuf, const u16* __restrict__ kbuf,
    const u16* __restrict__ vT, u16* __restrict__ obuf) {
  const int flat = blockIdx.y * gridDim.x + blockIdx.x;   // 512 total
  const int swz = (flat & 7) * 64 + (flat >> 3);          // XCD chunks of 64
  const int bh = swz >> 4, b = bh >> 4, h = bh & 15;
  const int q0 = (swz & 15) * 256;
  const int tid = threadIdx.x, lane = tid & 63, wid = tid >> 6;
  const int l31 = lane & 31, hi = lane >> 5;

  __shared__ __align__(16) u16 Ks0[64 * 128];
  __shared__ __align__(16) u16 Ks1[64 * 128];
  __shared__ __align__(16) u16 Vs0[128 * 64];
  __shared__ __align__(16) u16 Vs1[128 * 64];

  const size_t qkbase = (size_t)(b * SEQ) * DIMC + h * HD;
  const u16* Qp = qbuf + qkbase;
  const u16* Kp = kbuf + qkbase;
  const u16* Vp = vT + (size_t)(b * DIMC + h * HD) * SEQ;

  bf16x8 qf[8];
  const int qrow = q0 + wid * 32 + l31;
#pragma unroll
  for (int j = 0; j < 8; ++j)
    qf[j] = *(const bf16x8*)(Qp + (size_t)qrow * DIMC + j * 16 + hi * 8);

  float mq = -1e30f, lq = 0.f;
  f32x16 accO[4];
#pragma unroll
  for (int d = 0; d < 4; d++)
#pragma unroll
    for (int i = 0; i < 16; i++) accO[d][i] = 0.f;

  STAGE(Ks0, Vs0, 0);
  __syncthreads();

#pragma unroll 1
  for (int t = 0; t < SEQ / 64; t += 2) {
    STAGE(Ks1, Vs1, (t + 1) * 64);
    COMPUTE(Ks0, Vs0);
    __syncthreads();
    if (t + 2 < SEQ / 64) STAGE(Ks0, Vs0, (t + 2) * 64);
    COMPUTE(Ks1, Vs1);
    __syncthreads();
  }

  const float linv = 1.0f / lq;
  u16* Op = obuf + (size_t)(b * SEQ + q0 + wid * 32) * DIMC + h * HD;
#pragma unroll
  for (int r = 0; r < 16; r++) {
    const float lr = __shfl(linv, CROW(r));
    const int orow = CROW(r);
#pragma unroll
    for (int d = 0; d < 4; d++)
      Op[(size_t)orow * DIMC + d * 32 + l31] = f2bf(accO[d][r] * lr);
  }
}

// ---------------- launch ----------------
extern "C" void kernel_launch(void* const* d_in, const int* in_sizes, int n_in,
                              void* d_out, int out_size, void* d_ws, size_t ws_size,
                              hipStream_t stream) {
  const float* x     = (const float*)d_in[0];
  const float* freqs = (const float*)d_in[2];
  const float* wq = (const float*)d_in[3];
  const float* bq = (const float*)d_in[4];
  const float* wk = (const float*)d_in[5];
  const float* bk = (const float*)d_in[6];
  const float* wv = (const float*)d_in[7];
  const float* bv = (const float*)d_in[8];
  const float* wo = (const float*)d_in[9];
  const float* bo = (const float*)d_in[10];
  const float* gq = (const float*)d_in[11];
  const float* gk = (const float*)d_in[12];

  const size_t WS = (size_t)DIMC * DIMC;       // weight elems
  const size_t QS = (size_t)MTOK * DIMC;       // activation elems
  char* ws = (char*)d_ws;
  u16* xb  = (u16*)ws;  ws += QS * 2;
  u16* wb  = (u16*)ws;  ws += 4 * WS * 2;
  u16* qkv = (u16*)ws;  ws += 3 * QS * 2;
  u16* vT  = (u16*)ws;  ws += QS * 2;
  u16* ob  = (u16*)ws;  ws += QS * 2;

  cast_bf16_k<<<(int)(QS / 1024), 256, 0, stream>>>(x, xb, (int)QS);
  cast_w4_k<<<dim3((int)(WS / 1024), 1, 4), 256, 0, stream>>>(wq, wk, wv, wo, wb, (int)WS);

  // fused QKV: z selects weight/bias/output slice; z==2 writes transposed to vT
  gemm256_k<false><<<dim3(DIMC / 256, MTOK / 256, 3), 512, 0, stream>>>(
      xb, wb, bq, bk, bv, qkv, vT, WS, QS, DIMC, DIMC);

  rmsrope_k<<<MTOK, 256, 0, stream>>>(qkv, gq, gk, freqs);
  attn_k<<<dim3(SEQ / 256, BSZ * NH), 512, 0, stream>>>(qkv, qkv + 1 * QS, vT, ob);

  gemm256_k<true><<<dim3(DIMC / 256, MTOK / 256, 1), 512, 0, stream>>>(
      ob, wb + 3 * WS, bo, bo, bo, d_out, nullptr, 0, 0, DIMC, DIMC);
}